// Round 12
// baseline (246.447 us; speedup 1.0000x reference)
//
#include <hip/hip_runtime.h>

// ---------------- types / helpers ----------------
typedef __bf16 bf16;
typedef __attribute__((ext_vector_type(8)))  bf16     bf16x8;
typedef __attribute__((ext_vector_type(4)))  bf16     bf16x4;
typedef __attribute__((ext_vector_type(16))) float    f32x16;
typedef __attribute__((ext_vector_type(4)))  float    f32x4;
typedef __attribute__((ext_vector_type(4)))  unsigned uint4v;
typedef __attribute__((ext_vector_type(2)))  unsigned uint2v;

#define SLEN 4096
#define HDIM 64
#define EMB 512
#define NTILES 64            /* 64-kv tile count (mask word granularity) */
#define SCALE_LOG2E 0.1803336100254854f  /* 0.125 * log2(e), folded into Q at projection */

__device__ __forceinline__ f32x16 mfma32(bf16x8 a, bf16x8 b, f32x16 c) {
  return __builtin_amdgcn_mfma_f32_32x32x16_bf16(a, b, c, 0, 0, 0);
}

// async global->LDS, 16B per lane; LDS dest is wave-uniform base + lane*16
__device__ __forceinline__ void cp16(const void* g, const void* l) {
  __builtin_amdgcn_global_load_lds(
      (__attribute__((address_space(1))) unsigned int*)(unsigned long long)g,
      (__attribute__((address_space(3))) unsigned int*)(unsigned int)(unsigned long long)l,
      16, 0, 0);
}

__device__ __forceinline__ unsigned pk2(float a, float b) {
  unsigned short ua = __builtin_bit_cast(unsigned short, (bf16)a);
  unsigned short ub = __builtin_bit_cast(unsigned short, (bf16)b);
  return (unsigned)ua | ((unsigned)ub << 16);
}

// ---------------- kernel 1: QKV projections (MFMA), Q pre-scaled ----------------
__global__ __launch_bounds__(256, 2) void proj_qkv(
    const float* __restrict__ key, const float* __restrict__ query, const float* __restrict__ value,
    const float* __restrict__ Wq, const float* __restrict__ Wk, const float* __restrict__ Wv,
    bf16* __restrict__ Qb, bf16* __restrict__ Kb, bf16* __restrict__ VT)
{
  __shared__ __align__(16) bf16 tile[128][64];
  const int tid = threadIdx.x, w = tid >> 6, lane = tid & 63, l31 = lane & 31, lh = lane >> 5;
  const int r0 = blockIdx.x * 128;
  const int m0 = r0 + w * 32;

  #pragma unroll
  for (int p = 0; p < 3; ++p) {
    const float* X = (p == 0) ? query : (p == 1) ? key : value;
    const float* W = (p == 0) ? Wq    : (p == 1) ? Wk  : Wv;

    bf16x8 af[4];
    {
      const float* xr = X + (size_t)(m0 + l31) * 64 + 8 * lh;
      #pragma unroll
      for (int c = 0; c < 4; ++c) {
        f32x4 lo = *(const f32x4*)(xr + c * 16);
        f32x4 hi = *(const f32x4*)(xr + c * 16 + 4);
        bf16x8 v;
        #pragma unroll
        for (int j = 0; j < 4; ++j) { v[j] = (bf16)lo[j]; v[4 + j] = (bf16)hi[j]; }
        af[c] = v;
      }
    }
    bf16x8 bfr[2][4];
    #pragma unroll
    for (int nb = 0; nb < 2; ++nb) {
      const float* wr = W + (size_t)(l31 + 32 * nb) * 64 + 8 * lh;
      #pragma unroll
      for (int c = 0; c < 4; ++c) {
        f32x4 lo = *(const f32x4*)(wr + c * 16);
        f32x4 hi = *(const f32x4*)(wr + c * 16 + 4);
        bf16x8 v;
        #pragma unroll
        for (int j = 0; j < 4; ++j) { v[j] = (bf16)lo[j]; v[4 + j] = (bf16)hi[j]; }
        bfr[nb][c] = v;
      }
    }
    f32x16 a0, a1;
    #pragma unroll
    for (int r = 0; r < 16; ++r) { a0[r] = 0.f; a1[r] = 0.f; }
    #pragma unroll
    for (int c = 0; c < 4; ++c) {
      a0 = mfma32(af[c], bfr[0][c], a0);
      a1 = mfma32(af[c], bfr[1][c], a1);
    }

    const float qs = (p == 0) ? SCALE_LOG2E : 1.0f;
    __syncthreads();
    #pragma unroll
    for (int r = 0; r < 16; ++r) {
      const int row = w * 32 + (r & 3) + 8 * (r >> 2) + 4 * lh;
      tile[row][l31]      = (bf16)(a0[r] * qs);
      tile[row][l31 + 32] = (bf16)(a1[r] * qs);
    }
    __syncthreads();

    if (p < 2) {
      bf16* OUT = p ? Kb : Qb;
      const int rloc = tid >> 1, hf = tid & 1;
      const int rg = r0 + rloc, bs = rg >> 3, h = rg & 7, b = bs >> 12, sidx = bs & 4095;
      bf16* dst = OUT + (((size_t)(b * 8 + h) * SLEN + sidx) * 64 + hf * 32);
      const bf16* srcp = &tile[rloc][hf * 32];
      #pragma unroll
      for (int u = 0; u < 4; ++u) *(uint4v*)(dst + u * 8) = *(const uint4v*)(srcp + u * 8);
    } else {
      const int h = tid >> 5, d0 = tid & 31;
      const int b = blockIdx.x >> 8, s0 = (blockIdx.x * 16) & 4095;
      #pragma unroll
      for (int dh = 0; dh < 2; ++dh) {
        const int dd = d0 + 32 * dh;
        unsigned pk4[8];
        #pragma unroll
        for (int t2 = 0; t2 < 8; ++t2) {
          unsigned short ua = __builtin_bit_cast(unsigned short, tile[(2 * t2) * 8 + h][dd]);
          unsigned short ub = __builtin_bit_cast(unsigned short, tile[(2 * t2 + 1) * 8 + h][dd]);
          pk4[t2] = (unsigned)ua | ((unsigned)ub << 16);
        }
        bf16* dst = VT + ((size_t)(b * 8 + h) * 64 + dd) * SLEN + s0;
        uint4v A; A[0] = pk4[0]; A[1] = pk4[1]; A[2] = pk4[2]; A[3] = pk4[3];
        uint4v Bv; Bv[0] = pk4[4]; Bv[1] = pk4[5]; Bv[2] = pk4[6]; Bv[3] = pk4[7];
        *(uint4v*)(dst) = A;
        *(uint4v*)(dst + 8) = Bv;
      }
    }
  }
}

// ---------------- kernel 2: mask -> remapped 32-bit words ----------------
// MW[lh][tile64][q] : bit (kc*16 + r) = mask[q][tile64*64 + kc*32 + (r&3)+8*(r>>2)+4*lh]
__device__ __forceinline__ unsigned nib_compress(unsigned x) {
  x = (x | (x >> 4)) & 0x00FF00FFu;
  x = (x | (x >> 8)) & 0x0000FFFFu;
  return x;
}
__global__ void pack_mask(const int* __restrict__ mask, unsigned* __restrict__ MW)
{
  const int w = threadIdx.x >> 6, lane = threadIdx.x & 63;
  const int q = blockIdx.x * 4 + w;
  const int* row = mask + (size_t)q * SLEN;
  unsigned long long mine = 0ull;
  #pragma unroll 4
  for (int i = 0; i < 64; ++i) {
    unsigned long long b = __ballot(row[i * 64 + lane] != 0);
    if (i == lane) mine = b;
  }
  const unsigned lo = (unsigned)mine, hi = (unsigned)(mine >> 32);
  const unsigned w0 = nib_compress(lo & 0x0F0F0F0Fu)        | (nib_compress(hi & 0x0F0F0F0Fu) << 16);
  const unsigned w1 = nib_compress((lo >> 4) & 0x0F0F0F0Fu) | (nib_compress((hi >> 4) & 0x0F0F0F0Fu) << 16);
  MW[(size_t)lane * SLEN + q] = w0;                              // lh = 0 plane
  MW[(size_t)NTILES * SLEN + (size_t)lane * SLEN + q] = w1;      // lh = 1 plane
}

// ---------------- kernel 3: Wo -> hi/lo bf16 planes ----------------
__global__ void wo_split(const float* __restrict__ Wo, bf16* __restrict__ WH, bf16* __restrict__ WL)
{
  const int i = (blockIdx.x * 256 + threadIdx.x) * 4;
  f32x4 v = *(const f32x4*)(Wo + i);
  bf16x4 h, l;
  #pragma unroll
  for (int j = 0; j < 4; ++j) { h[j] = (bf16)v[j]; l[j] = (bf16)(v[j] - (float)h[j]); }
  *(bf16x4*)(WH + i) = h;
  *(bf16x4*)(WL + i) = l;
}

// ---------------- kernel 4: flash attention — r11 structure + kv-split x2 ----------------
// Grid 2048: block = (half, bh, qt). 2 waves x 32 q rows, 2048 kv per block.
// 16KB LDS: buf[2] x [K 4K | V 4K]. Per tile: STAGE(next) -> vmcnt(4) -> s_barrier
// -> TILEC -> s_barrier. Max-free softmax => partials linear; f32 partial O + lsum
// written per half; combine_halves merges (structure verified in r6).
__global__ __launch_bounds__(128, 4) void attn_kernel(
    const bf16* __restrict__ Qb, const bf16* __restrict__ Kb, const bf16* __restrict__ VT,
    const unsigned* __restrict__ MW,
    float* __restrict__ PO, float* __restrict__ PLg)
{
  __shared__ __align__(16) unsigned char smem[16384];

  const int tid = threadIdx.x, w = tid >> 6, lane = tid & 63, l31 = lane & 31, lh = lane >> 5;
  // XCD swizzle (bijective: 2048 % 8 == 0): each XCD gets 256 consecutive logicals
  // = 4 bh's of one half => KV working set ~2MB fits the 4MB per-XCD L2.
  const int logical = (blockIdx.x & 7) * 256 + (blockIdx.x >> 3);
  const int qt = logical & 63, bh = (logical >> 6) & 15, half = logical >> 10;
  const int q0w = qt * 64 + w * 32;
  const int qrow = q0w + l31;
  const int kv0 = half * 2048;

  // Q fragments (B operand: lane&31 = q, k-slot = 16c+8lh+j), pre-scaled
  const bf16* qp = Qb + ((size_t)bh * SLEN + qrow) * HDIM + 8 * lh;
  const bf16x8 qf0 = *(const bf16x8*)(qp);
  const bf16x8 qf1 = *(const bf16x8*)(qp + 16);
  const bf16x8 qf2 = *(const bf16x8*)(qp + 32);
  const bf16x8 qf3 = *(const bf16x8*)(qp + 48);

  // staging sources; wave w owns K frags c={2w,2w+1}, V frags f={2w,2w+1}
  const bf16* kp0 = Kb + ((size_t)bh * SLEN + kv0 + l31) * HDIM + (2 * w) * 16 + 8 * lh;
  const bf16* kp1 = kp0 + 16;
  const bf16* vp0 = VT + ((size_t)bh * HDIM + w * 32 + l31) * SLEN + kv0 + 8 * lh;
  const bf16* vp1 = vp0 + 16;

  const int fk = 2 * w * 1024;          // K staging dst offset within buffer
  const int fv = 4096 + 2 * w * 1024;   // V staging dst offset
  const int lb = lane * 16;

  f32x16 o0, o1, Z16;
  #pragma unroll
  for (int r = 0; r < 16; ++r) { o0[r] = 0.f; o1[r] = 0.f; Z16[r] = 0.f; }
  float la0 = 0.f, la1 = 0.f, la2 = 0.f, la3 = 0.f;

#define STAGE(BUF) { \
  cp16(kp0, smem + (BUF) * 8192 + fk); cp16(kp1, smem + (BUF) * 8192 + fk + 1024); \
  cp16(vp0, smem + (BUF) * 8192 + fv); cp16(vp1, smem + (BUF) * 8192 + fv + 1024); \
  kp0 += 2048; kp1 += 2048; vp0 += 32; vp1 += 32; \
}

#define TILEC(BUF, MWORD, SH) { \
  const unsigned char* kr = smem + (BUF) * 8192 + lb; \
  __builtin_amdgcn_s_setprio(1); \
  f32x16 s = mfma32(*(const bf16x8*)(kr), qf0, Z16); \
  s = mfma32(*(const bf16x8*)(kr + 1024), qf1, s); \
  s = mfma32(*(const bf16x8*)(kr + 2048), qf2, s); \
  s = mfma32(*(const bf16x8*)(kr + 3072), qf3, s); \
  __builtin_amdgcn_s_setprio(0); \
  const unsigned mwk = (MWORD) >> (SH); \
  float p[16]; \
  _Pragma("unroll") \
  for (int r = 0; r < 16; ++r) { \
    float e = __builtin_amdgcn_exp2f(s[r]); \
    unsigned kbit = (unsigned)(((int)(mwk << (31 - r))) >> 31); \
    e = __builtin_bit_cast(float, __builtin_bit_cast(unsigned, e) & kbit); \
    p[r] = e; \
    if ((r & 3) == 0) la0 += e; else if ((r & 3) == 1) la1 += e; \
    else if ((r & 3) == 2) la2 += e; else la3 += e; \
  } \
  bf16x8 bp0, bp1; \
  { unsigned Wa = pk2(p[0], p[1]), Wb = pk2(p[2], p[3]); \
    unsigned Wc = pk2(p[4], p[5]), Wd = pk2(p[6], p[7]); \
    uint2v s02 = __builtin_amdgcn_permlane32_swap(Wa, Wc, false, false); \
    uint2v s13 = __builtin_amdgcn_permlane32_swap(Wb, Wd, false, false); \
    uint4v fw; fw[0] = s02[0]; fw[1] = s13[0]; fw[2] = s02[1]; fw[3] = s13[1]; \
    bp0 = __builtin_bit_cast(bf16x8, fw); } \
  { unsigned Wa = pk2(p[8], p[9]), Wb = pk2(p[10], p[11]); \
    unsigned Wc = pk2(p[12], p[13]), Wd = pk2(p[14], p[15]); \
    uint2v s02 = __builtin_amdgcn_permlane32_swap(Wa, Wc, false, false); \
    uint2v s13 = __builtin_amdgcn_permlane32_swap(Wb, Wd, false, false); \
    uint4v fw; fw[0] = s02[0]; fw[1] = s13[0]; fw[2] = s02[1]; fw[3] = s13[1]; \
    bp1 = __builtin_bit_cast(bf16x8, fw); } \
  const unsigned char* vr = kr + 4096; \
  __builtin_amdgcn_s_setprio(1); \
  o0 = mfma32(*(const bf16x8*)(vr), bp0, o0); \
  o0 = mfma32(*(const bf16x8*)(vr + 1024), bp1, o0); \
  o1 = mfma32(*(const bf16x8*)(vr + 2048), bp0, o1); \
  o1 = mfma32(*(const bf16x8*)(vr + 3072), bp1, o1); \
  __builtin_amdgcn_s_setprio(0); \
}

#define SYNC_STAGED \
  asm volatile("s_waitcnt vmcnt(4)" ::: "memory"); \
  __builtin_amdgcn_sched_barrier(0); \
  __builtin_amdgcn_s_barrier(); \
  __builtin_amdgcn_sched_barrier(0);

#define SYNC_READ_DONE \
  __builtin_amdgcn_sched_barrier(0); \
  __builtin_amdgcn_s_barrier(); \
  __builtin_amdgcn_sched_barrier(0);

  // mask word stream (tracked loads, 1 pair ahead), offset to this half's tiles
  const unsigned* mp = MW + (size_t)lh * NTILES * SLEN + (size_t)(half * 32) * SLEN + qrow;

  STAGE(0)                       // tile 0 -> buf0
  unsigned mwc = *mp;            // word for pair 0 (tracked)

  for (int t2 = 0; t2 < 32; ++t2) {
    STAGE(1)                     // tile 2*t2+1 -> buf1
    SYNC_STAGED                  // tile 2*t2 resident
    const unsigned mwn = mp[(t2 < 31) ? SLEN : 0];     // next pair's word (tracked)
    TILEC(0, mwc, 0)             // compute tile 2*t2
    SYNC_READ_DONE               // buf0 safe to overwrite

    STAGE(0)                     // tile 2*t2+2 -> buf0 (dummy at t2==31: lands in ws)
    SYNC_STAGED                  // tile 2*t2+1 resident
    TILEC(1, mwc, 16)            // compute tile 2*t2+1
    SYNC_READ_DONE               // buf1 safe to overwrite

    mwc = mwn; mp += SLEN;
  }
#undef STAGE
#undef TILEC
#undef SYNC_STAGED
#undef SYNC_READ_DONE

  // drain dummy stage, sync partner before LDS reuse
  asm volatile("s_waitcnt vmcnt(0)" ::: "memory");
  __builtin_amdgcn_s_barrier();

  // ---- wave-private epilogue: two-pass f32 transpose, write partial O + lsum ----
  float plsum = (la0 + la1) + (la2 + la3);
  plsum += __shfl_xor(plsum, 32);

  float* T = (float*)(smem + w * 8192);   // [32 q][33 f32] = 4224B per wave
  const int qq = lane >> 1, hx = lane & 1;
  float* dst = PO + ((size_t)((half * 16 + bh) * SLEN + q0w + qq)) * 64 + hx * 16;
  const float* sp = T + qq * 33 + hx * 16;

  // pass 1: o0 -> d 0..31
  #pragma unroll
  for (int r = 0; r < 16; ++r) {
    const int dr = (r & 3) + 8 * (r >> 2) + 4 * lh;
    T[l31 * 33 + dr] = o0[r];
  }
  #pragma unroll
  for (int u = 0; u < 4; ++u) *(f32x4*)(dst + u * 4) = *(const f32x4*)(sp + u * 4);
  // pass 2: o1 -> d 32..63
  #pragma unroll
  for (int r = 0; r < 16; ++r) {
    const int dr = (r & 3) + 8 * (r >> 2) + 4 * lh;
    T[l31 * 33 + dr] = o1[r];
  }
  #pragma unroll
  for (int u = 0; u < 4; ++u) *(f32x4*)(dst + 32 + u * 4) = *(const f32x4*)(sp + u * 4);

  if (lane < 32) PLg[(size_t)(half * 16 + bh) * SLEN + q0w + l31] = plsum;
}

// ---------------- kernel 4b: combine the two kv halves (verified in r6) ----------------
__global__ __launch_bounds__(256) void combine_halves(
    const float* __restrict__ PO, const float* __restrict__ PLg,
    bf16* __restrict__ CH, bf16* __restrict__ CL)
{
  const int bh = blockIdx.x >> 5, qt = blockIdx.x & 31;
  const int t = threadIdx.x;
  const int q = qt * 128 + (t >> 1);
  const size_t HOFF = (size_t)16 * SLEN * 64;
  const size_t base = ((size_t)bh * SLEN + q) * 64 + (t & 1) * 32;
  const float inv = 1.f / (PLg[(size_t)bh * SLEN + q] +
                           PLg[(size_t)16 * SLEN + (size_t)bh * SLEN + q]);
  const float* p0 = PO + base;
  const float* p1 = PO + HOFF + base;
  unsigned hw[16], lw[16];
  #pragma unroll
  for (int i = 0; i < 8; ++i) {
    f32x4 a = *(const f32x4*)(p0 + i * 4);
    f32x4 b = *(const f32x4*)(p1 + i * 4);
    float v0 = (a[0] + b[0]) * inv, v1 = (a[1] + b[1]) * inv;
    float v2 = (a[2] + b[2]) * inv, v3 = (a[3] + b[3]) * inv;
    float h0 = (float)(bf16)v0, h1 = (float)(bf16)v1;
    float h2 = (float)(bf16)v2, h3 = (float)(bf16)v3;
    hw[i * 2]     = pk2(v0, v1);
    hw[i * 2 + 1] = pk2(v2, v3);
    lw[i * 2]     = pk2(v0 - h0, v1 - h1);
    lw[i * 2 + 1] = pk2(v2 - h2, v3 - h3);
  }
  bf16* ch = CH + base;
  bf16* cl = CL + base;
  #pragma unroll
  for (int u = 0; u < 4; ++u) {
    uint4v H; H[0] = hw[u*4]; H[1] = hw[u*4+1]; H[2] = hw[u*4+2]; H[3] = hw[u*4+3];
    uint4v L; L[0] = lw[u*4]; L[1] = lw[u*4+1]; L[2] = lw[u*4+2]; L[3] = lw[u*4+3];
    *(uint4v*)(ch + u * 8) = H;
    *(uint4v*)(cl + u * 8) = L;
  }
}

// ---------------- kernel 5: output projection (hi/lo split GEMM) ----------------
__global__ __launch_bounds__(256, 2) void out_proj(
    const bf16* __restrict__ CH, const bf16* __restrict__ CL,
    const bf16* __restrict__ WH, const bf16* __restrict__ WL,
    const float* __restrict__ bo, float* __restrict__ out)
{
  __shared__ __align__(16) bf16 Af[2][4][4][64][8];  // 32KB
  const int tid = threadIdx.x, w = tid >> 6, lane = tid & 63, l31 = lane & 31, lh = lane >> 5;
  const int mt = blockIdx.x >> 3, nt = blockIdx.x & 7;
  const int bs0 = mt * 128, n0 = nt * 64;
  const int b = bs0 >> 12, sbase = bs0 & 4095;

  f32x16 a0, a1;
  #pragma unroll
  for (int r = 0; r < 16; ++r) { a0[r] = 0.f; a1[r] = 0.f; }

  for (int kk = 0; kk < 8; ++kk) {
    __syncthreads();
    #pragma unroll
    for (int qq = 0; qq < 8; ++qq) {
      const int fid = w * 8 + qq, pl = fid >> 4, mb = (fid >> 2) & 3, c = fid & 3;
      const bf16* src = (pl ? CL : CH) +
          ((size_t)(b * 8 + kk) * SLEN + sbase + 32 * mb + l31) * 64 + 16 * c + 8 * lh;
      cp16(src, &Af[pl][mb][c][0][0]);
    }
    __syncthreads();

    bf16x8 bh0[4], bl0[4], bh1[4], bl1[4], ah[4], al[4];
    #pragma unroll
    for (int c = 0; c < 4; ++c) {
      const size_t o0off = (size_t)(n0 + l31) * EMB + kk * 64 + 16 * c + 8 * lh;
      const size_t o1off = (size_t)(n0 + l31 + 32) * EMB + kk * 64 + 16 * c + 8 * lh;
      bh0[c] = *(const bf16x8*)(WH + o0off);
      bl0[c] = *(const bf16x8*)(WL + o0off);
      bh1[c] = *(const bf16x8*)(WH + o1off);
      bl1[c] = *(const bf16x8*)(WL + o1off);
      ah[c] = *(const bf16x8*)(&Af[0][w][c][lane][0]);
      al[c] = *(const bf16x8*)(&Af[1][w][c][lane][0]);
    }
    #pragma unroll
    for (int c = 0; c < 4; ++c) {
      a0 = mfma32(ah[c], bh0[c], a0);
      a0 = mfma32(ah[c], bl0[c], a0);
      a0 = mfma32(al[c], bh0[c], a0);
      a1 = mfma32(ah[c], bh1[c], a1);
      a1 = mfma32(ah[c], bl1[c], a1);
      a1 = mfma32(al[c], bh1[c], a1);
    }
  }

  const float bv0 = bo[n0 + l31], bv1 = bo[n0 + l31 + 32];
  #pragma unroll
  for (int r = 0; r < 16; ++r) {
    const int row = bs0 + w * 32 + (r & 3) + 8 * (r >> 2) + 4 * lh;
    out[(size_t)row * EMB + n0 + l31]      = a0[r] + bv0;
    out[(size_t)row * EMB + n0 + l31 + 32] = a1[r] + bv1;
  }
}

// ---------------- launch ----------------
extern "C" void kernel_launch(void* const* d_in, const int* in_sizes, int n_in,
                              void* d_out, int out_size, void* d_ws, size_t ws_size,
                              hipStream_t stream)
{
  (void)in_sizes; (void)n_in; (void)out_size; (void)ws_size;
  const float* key   = (const float*)d_in[0];
  const float* query = (const float*)d_in[1];
  const float* value = (const float*)d_in[2];
  const int*   mask  = (const int*)d_in[3];
  const float* Wq    = (const float*)d_in[4];
  const float* Wk    = (const float*)d_in[5];
  const float* Wv    = (const float*)d_in[6];
  const float* Wo    = (const float*)d_in[7];
  const float* bo    = (const float*)d_in[8];
  float* out = (float*)d_out;

  char* ws = (char*)d_ws;
  bf16* Qb = (bf16*)(ws);                       // 8 MB  [BH][S][64] (pre-scaled)
  bf16* Kb = (bf16*)(ws + (8ull  << 20));       // 8 MB  [BH][S][64]
  bf16* VT = (bf16*)(ws + (16ull << 20));       // 8 MB  [BH][64][S]
  unsigned* MW = (unsigned*)(ws + (24ull << 20));  // 2 MB [lh][tile64][q]
  bf16* CH = (bf16*)(ws + (26ull << 20));       // 8 MB  ctx hi
  bf16* CL = (bf16*)(ws + (34ull << 20));       // 8 MB  ctx lo
  bf16* WH = (bf16*)(ws + (42ull << 20));       // 512 KB
  bf16* WL = (bf16*)(ws + (42ull << 20) + (512ull << 10));
  float* PO  = (float*)(ws + (44ull << 20));    // [2][16][4096][64] f32 = 33.6 MB
  float* PLg = (float*)(ws + (78ull << 20));    // [2][16][4096] f32

  proj_qkv<<<512, 256, 0, stream>>>(key, query, value, Wq, Wk, Wv, Qb, Kb, VT);
  pack_mask<<<1024, 256, 0, stream>>>(mask, MW);
  wo_split<<<256, 256, 0, stream>>>(Wo, WH, WL);
  attn_kernel<<<2048, 128, 0, stream>>>(Qb, Kb, VT, MW, PO, PLg);
  combine_halves<<<512, 256, 0, stream>>>(PO, PLg, CH, CL);
  out_proj<<<512, 256, 0, stream>>>(CH, CL, WH, WL, bo, out);
}